// Round 1
// baseline (647.613 us; speedup 1.0000x reference)
//
#include <hip/hip_runtime.h>
#include <hip/hip_bf16.h>
#include <stdint.h>

// ---------------- problem constants ----------------
#define N_NODES 512
#define N_EDGES 8192
#define D       2048
#define C_N     151
#define C_E     51
#define NMS_TH  0.3f

// output float offsets (raw_edge_class, h_edge_emb, raw_node_class, h_node_emb)
#define O_REC 0
#define O_HEE 417792          // 8192*51
#define O_RNC 17195008        // + 8192*2048
#define O_HNE 17272320        // + 512*151
// total out = 18320896 floats

// workspace float offsets
#define W_ATT 0               // att / att_masked [512][151] (masked in place)
#define W_SCT 77312           // schemaT [151][2048]
#define W_NP  386560          // node-gemm partials [8][512][151]
// ws bytes needed = (386560 + 8*77312)*4 = 4,019,712 B

// =====================================================================
// Edge GEMM: C[8192][51] = A[8192][2048] @ B[2048][51]
// 32 rows/block (4 waves, 8 rows/wave), lane = class (51 of 64 active).
// B tile stored transposed [c][kk] with stride 68 so the per-lane read is a
// conflict-acceptable ds_read_b128 over kk; A fragments are uniform
// (broadcast) ds_read_b128.
// =====================================================================
#define EG_BK 64
__global__ __launch_bounds__(256) void edge_gemm(const float* __restrict__ A,
                                                 const float* __restrict__ Bm,
                                                 float* __restrict__ C) {
    __shared__ float Bs[C_E][EG_BK + 4];   // [51][68] = 13.9 KB
    __shared__ float As[32][EG_BK];        // 8 KB
    const int tid  = threadIdx.x;
    const int w    = tid >> 6;
    const int lane = tid & 63;
    const int row0 = blockIdx.x * 32;
    const int cl   = (lane < C_E) ? lane : (C_E - 1);  // clamp pad lanes

    float acc[8] = {0.f, 0.f, 0.f, 0.f, 0.f, 0.f, 0.f, 0.f};

    for (int k0 = 0; k0 < D; k0 += EG_BK) {
        // stage B chunk: 64*51 floats, global-contiguous
        for (int i = tid; i < EG_BK * C_E; i += 256) {
            Bs[i % C_E][i / C_E] = Bm[k0 * C_E + i];
        }
        // stage A: 32 rows x 64 k = 512 float4, 2 per thread
        {
            int ar = tid >> 4;
            int ak = (tid & 15) << 2;
            *(float4*)&As[ar][ak] =
                *(const float4*)(A + (size_t)(row0 + ar) * D + k0 + ak);
            ar += 16;
            *(float4*)&As[ar][ak] =
                *(const float4*)(A + (size_t)(row0 + ar) * D + k0 + ak);
        }
        __syncthreads();

        #pragma unroll
        for (int kk = 0; kk < EG_BK; kk += 4) {
            const float4 bv = *(const float4*)&Bs[cl][kk];
            #pragma unroll
            for (int j = 0; j < 8; ++j) {
                const float4 av = *(const float4*)&As[w * 8 + j][kk];
                acc[j] = fmaf(av.x, bv.x, acc[j]);
                acc[j] = fmaf(av.y, bv.y, acc[j]);
                acc[j] = fmaf(av.z, bv.z, acc[j]);
                acc[j] = fmaf(av.w, bv.w, acc[j]);
            }
        }
        __syncthreads();
    }

    if (lane < C_E) {
        #pragma unroll
        for (int j = 0; j < 8; ++j)
            C[(size_t)(row0 + w * 8 + j) * C_E + lane] = acc[j];
    }
}

// =====================================================================
// Node GEMM partials: P[s][512][151], s = k-chunk of 256.
// Block: 8 rows x 192 threads (lane = class, 151 active). Deterministic
// (no atomics); partials reduced in softmax kernel in fixed order.
// =====================================================================
__global__ __launch_bounds__(192) void node_gemm(const float* __restrict__ A,
                                                 const float* __restrict__ S,
                                                 float* __restrict__ P) {
    __shared__ float Bs[32][152];   // 19.5 KB
    __shared__ float As[8][32];
    const int tid = threadIdx.x;
    const int r0  = blockIdx.x * 8;
    const int k0  = blockIdx.y * 256;
    const int cc  = (tid < C_N) ? tid : 0;

    float acc[8] = {0.f, 0.f, 0.f, 0.f, 0.f, 0.f, 0.f, 0.f};

    for (int ks = 0; ks < 256; ks += 32) {
        const int kb = k0 + ks;
        for (int i = tid; i < 32 * C_N; i += 192) {
            Bs[i / C_N][i % C_N] = S[(size_t)kb * C_N + i];
        }
        if (tid < 64) {
            const int rr = tid >> 3;
            const int ak = (tid & 7) << 2;
            *(float4*)&As[rr][ak] =
                *(const float4*)(A + (size_t)(r0 + rr) * D + kb + ak);
        }
        __syncthreads();
        #pragma unroll 8
        for (int kk = 0; kk < 32; ++kk) {
            const float b = Bs[kk][cc];
            #pragma unroll
            for (int j = 0; j < 8; ++j)
                acc[j] = fmaf(As[j][kk], b, acc[j]);
        }
        __syncthreads();
    }

    if (tid < C_N) {
        float* out = P + (size_t)blockIdx.y * (N_NODES * C_N);
        #pragma unroll
        for (int j = 0; j < 8; ++j)
            out[(size_t)(r0 + j) * C_N + tid] = acc[j];
    }
}

// =====================================================================
// schemaT[151][2048] = nodes_schema[2048][151]^T
// =====================================================================
__global__ __launch_bounds__(256) void transpose_k(const float* __restrict__ S,
                                                   float* __restrict__ ST) {
    const int c = blockIdx.x;
    for (int d = threadIdx.x; d < D; d += 256)
        ST[(size_t)c * D + d] = S[(size_t)d * C_N + c];
}

// =====================================================================
// Reduce node partials -> raw_node_class, then row softmax -> att.
// One wave per row. att[:,0] stored as 0 (background class masked).
// =====================================================================
__global__ __launch_bounds__(256) void softmax_k(const float* __restrict__ np,
                                                 float* __restrict__ raw_out,
                                                 float* __restrict__ att) {
    const int w    = threadIdx.x >> 6;
    const int lane = threadIdx.x & 63;
    const int r    = blockIdx.x * 4 + w;
    const size_t base = (size_t)r * C_N;

    float v0 = 0.f, v1 = 0.f, v2 = 0.f;
    #pragma unroll
    for (int s = 0; s < 8; ++s) {
        const float* p = np + (size_t)s * (N_NODES * C_N) + base;
        v0 += p[lane];
        v1 += p[64 + lane];
        if (lane < C_N - 128) v2 += p[128 + lane];
    }
    raw_out[base + lane]      = v0;
    raw_out[base + 64 + lane] = v1;
    if (lane < C_N - 128) raw_out[base + 128 + lane] = v2;

    float m = fmaxf(v0, v1);
    if (lane < C_N - 128) m = fmaxf(m, v2);
    #pragma unroll
    for (int o = 32; o; o >>= 1) m = fmaxf(m, __shfl_xor(m, o));

    const float e0 = expf(v0 - m);
    const float e1 = expf(v1 - m);
    const float e2 = (lane < C_N - 128) ? expf(v2 - m) : 0.f;
    float ssum = e0 + e1 + e2;
    #pragma unroll
    for (int o = 32; o; o >>= 1) ssum += __shfl_xor(ssum, o);

    att[base + lane]      = (lane == 0) ? 0.f : (e0 / ssum);
    att[base + 64 + lane] = e1 / ssum;
    if (lane < C_N - 128) att[base + 128 + lane] = e2 / ssum;
}

// =====================================================================
// Per-class NMS. One block per class c in [1,150].
// 1) load 512 scores (att col c), bitonic sort (score desc, idx asc)
//    == stable argsort(-scores)
// 2) parallel suppression bitmask: msk[i][w] bit b = IoU(i, w*64+b)>0.3, j>i
// 3) wave-serial greedy scan (lane w owns word w of `removed`)
// 4) write att col c masked (in place)
// =====================================================================
__global__ __launch_bounds__(256) void nms_k(float* __restrict__ att,
                                             const float* __restrict__ boxes) {
    const int c = blockIdx.x + 1;
    __shared__ float  ss[512];
    __shared__ int    si[512];
    __shared__ float4 bs[512];
    __shared__ float  area[512];
    __shared__ unsigned long long msk[512][8];
    __shared__ unsigned long long rem[8];
    const int tid = threadIdx.x;

    for (int i = tid; i < 512; i += 256) {
        ss[i] = att[(size_t)i * C_N + c];
        si[i] = i;
    }
    __syncthreads();

    // bitonic sort: comes-first == (score higher) or (equal and index lower)
    for (int k = 2; k <= 512; k <<= 1) {
        for (int j = k >> 1; j > 0; j >>= 1) {
            for (int i = tid; i < 512; i += 256) {
                const int ixj = i ^ j;
                if (ixj > i) {
                    const float sa = ss[i], sb = ss[ixj];
                    const int ia = si[i], ib = si[ixj];
                    const bool aFirst = (sa > sb) || (sa == sb && ia < ib);
                    const bool up = ((i & k) == 0);
                    if (up ? !aFirst : aFirst) {
                        ss[i] = sb; ss[ixj] = sa;
                        si[i] = ib; si[ixj] = ia;
                    }
                }
            }
            __syncthreads();
        }
    }

    // gather sorted boxes + areas
    for (int i = tid; i < 512; i += 256) {
        const float4 b = *(const float4*)(boxes + ((size_t)si[i] * C_N + c) * 4);
        bs[i] = b;
        area[i] = (b.z - b.x) * (b.w - b.y);
    }
    __syncthreads();

    // suppression bitmasks
    for (int Wd = tid; Wd < 512 * 8; Wd += 256) {
        const int i = Wd >> 3;
        const int w = Wd & 7;
        unsigned long long m = 0ull;
        const int j0 = w * 64;
        if (j0 + 63 > i) {
            const float4 bi = bs[i];
            const float  ai = area[i];
            const int bstart = (i + 1 > j0) ? (i + 1 - j0) : 0;
            for (int b = bstart; b < 64; ++b) {
                const int j = j0 + b;
                const float4 bj = bs[j];
                const float lx = fmaxf(bi.x, bj.x);
                const float ly = fmaxf(bi.y, bj.y);
                const float rx = fminf(bi.z, bj.z);
                const float ry = fminf(bi.w, bj.w);
                const float ww = fmaxf(rx - lx, 0.f);
                const float hh = fmaxf(ry - ly, 0.f);
                const float inter = ww * hh;
                const float iou = inter / (ai + area[j] - inter + 1e-9f);
                if (iou > NMS_TH) m |= (1ull << b);
            }
        }
        msk[i][w] = m;
    }
    __syncthreads();

    // greedy scan: lane w owns removed word w; keep-bit broadcast via shfl
    if (tid < 64) {
        const int w = tid & 7;
        unsigned long long r = 0ull;
        for (int i = 0; i < 512; ++i) {
            const unsigned long long ri = __shfl(r, i >> 6);
            const bool keep = !((ri >> (i & 63)) & 1ull);
            if (keep) r |= msk[i][w];
        }
        if (tid < 8) rem[tid] = r;
    }
    __syncthreads();

    // write masked column (in place on att)
    for (int p = tid; p < 512; p += 256) {
        const bool kp = !((rem[p >> 6] >> (p & 63)) & 1ull);
        att[(size_t)si[p] * C_N + c] = kp ? ss[p] : 0.f;
    }
}

// =====================================================================
// h_node_emb[512][2048] = att_masked[512][151] @ schemaT[151][2048]
// Block: 8 rows x 256 d-columns; grid (8 d-chunks, 64 row-groups).
// =====================================================================
__global__ __launch_bounds__(256) void hnode_k(const float* __restrict__ attm,
                                               const float* __restrict__ ST,
                                               float* __restrict__ H) {
    __shared__ float al[8][C_N + 1];
    const int r0 = blockIdx.y * 8;
    const int d  = blockIdx.x * 256 + threadIdx.x;

    for (int i = threadIdx.x; i < 8 * C_N; i += 256) {
        al[i / C_N][i % C_N] = attm[(size_t)r0 * C_N + i];
    }
    __syncthreads();

    float acc[8] = {0.f, 0.f, 0.f, 0.f, 0.f, 0.f, 0.f, 0.f};
    for (int cc = 0; cc < C_N; ++cc) {
        const float s = ST[(size_t)cc * D + d];
        #pragma unroll
        for (int j = 0; j < 8; ++j)
            acc[j] = fmaf(al[j][cc], s, acc[j]);
    }
    #pragma unroll
    for (int j = 0; j < 8; ++j)
        H[(size_t)(r0 + j) * D + d] = acc[j];
}

// =====================================================================
extern "C" void kernel_launch(void* const* d_in, const int* in_sizes, int n_in,
                              void* d_out, int out_size, void* d_ws, size_t ws_size,
                              hipStream_t stream) {
    (void)in_sizes; (void)n_in; (void)out_size; (void)ws_size;
    const float* node_emb     = (const float*)d_in[0];
    const float* edge_emb     = (const float*)d_in[1];
    const float* boxes        = (const float*)d_in[6];
    const float* nodes_schema = (const float*)d_in[7];
    const float* edges_schema = (const float*)d_in[8];
    float* out = (float*)d_out;
    float* ws  = (float*)d_ws;

    float* att = ws + W_ATT;
    float* sct = ws + W_SCT;
    float* np  = ws + W_NP;

    // h_edge_emb is exactly zero (edge att masked out entirely in reference)
    hipMemsetAsync(out + O_HEE, 0, (size_t)(N_EDGES * D) * sizeof(float), stream);

    edge_gemm<<<N_EDGES / 32, 256, 0, stream>>>(edge_emb, edges_schema, out + O_REC);
    node_gemm<<<dim3(N_NODES / 8, 8), 192, 0, stream>>>(node_emb, nodes_schema, np);
    transpose_k<<<C_N, 256, 0, stream>>>(nodes_schema, sct);
    softmax_k<<<N_NODES / 4, 256, 0, stream>>>(np, out + O_RNC, att);
    nms_k<<<C_N - 1, 256, 0, stream>>>(att, boxes);
    hnode_k<<<dim3(D / 256, N_NODES / 8), 256, 0, stream>>>(att, sct, out + O_HNE);
}

// Round 3
// 490.719 us; speedup vs baseline: 1.3197x; 1.3197x over previous
//
#include <hip/hip_runtime.h>
#include <hip/hip_bf16.h>
#include <stdint.h>

// ---------------- problem constants ----------------
#define N_NODES 512
#define N_EDGES 8192
#define D       2048
#define C_N     151
#define C_E     51
#define NMS_TH  0.3f

// output float offsets (raw_edge_class, h_edge_emb, raw_node_class, h_node_emb)
#define O_REC 0
#define O_HEE 417792          // 8192*51
#define O_RNC 17195008        // + 8192*2048
#define O_HNE 17272320        // + 512*151

// workspace float offsets
#define W_ATT 0               // att / att_masked [512][151]
#define W_SCT 77312           // schemaT [151][2048]
#define W_NP  386560          // node-gemm partials [8][512][151]
// ws bytes = (386560 + 8*512*151)*4 ≈ 4.02 MB

// =====================================================================
// Edge GEMM: C[8192][51] += A[8192][2048] @ B[2048][51]   (C pre-zeroed)
// Register-tiled f32: block 256 thr (16 tr x 16 tc), thread tile 8x4,
// BM=128, BN=64 (51 real), K-split x8 (256 K per block), inner BK=32.
// Per kk per thread: 3 ds_read_b128 -> 32 FMAs (ratio 10.7 FMA/lds-op).
// A staged transposed As[k][row] (pad 132): a-frag reads are 16-lane
// broadcast, conflict-free; b-frag 2-way (free).
// =====================================================================
#define EG_BM  128
#define EG_BKI 32
#define EG_KSPAN 256
__global__ __launch_bounds__(256) void edge_gemm(const float* __restrict__ A,
                                                 const float* __restrict__ Bm,
                                                 float* __restrict__ C) {
    __shared__ float As[EG_BKI][EG_BM + 4];   // [32][132] 16.9 KB
    __shared__ float Bs[EG_BKI][68];          // [32][68]   8.7 KB
    const int tid  = threadIdx.x;
    const int tr   = tid >> 4;                // 0..15 -> rows tr*8..+7
    const int tc   = tid & 15;                // 0..15 -> cols tc*4..+3
    const int row0 = blockIdx.x * EG_BM;
    const int kb   = blockIdx.y * EG_KSPAN;

    float acc[8][4];
    #pragma unroll
    for (int m = 0; m < 8; ++m)
        #pragma unroll
        for (int n = 0; n < 4; ++n) acc[m][n] = 0.f;

    for (int k0 = 0; k0 < EG_KSPAN; k0 += EG_BKI) {
        // stage A: 128 rows x 32 k = 1024 float4, 4 per thread (coalesced)
        #pragma unroll
        for (int j = 0; j < 4; ++j) {
            const int f   = tid + 256 * j;
            const int row = f >> 3;           // 8 float4 per row
            const int kq  = f & 7;
            const float4 v = *(const float4*)(A + (size_t)(row0 + row) * D + kb + k0 + kq * 4);
            As[kq * 4 + 0][row] = v.x;
            As[kq * 4 + 1][row] = v.y;
            As[kq * 4 + 2][row] = v.z;
            As[kq * 4 + 3][row] = v.w;
        }
        // stage B: 32 k x 64 cols (pad c>=51 with 0)
        #pragma unroll
        for (int j = 0; j < 8; ++j) {
            const int e = tid + 256 * j;
            const int k = e >> 6;
            const int c = e & 63;
            Bs[k][c] = (c < C_E) ? Bm[(size_t)(kb + k0 + k) * C_E + c] : 0.f;
        }
        __syncthreads();

        #pragma unroll 8
        for (int kk = 0; kk < EG_BKI; ++kk) {
            float a[8], b[4];
            *(float4*)&a[0] = *(const float4*)&As[kk][tr * 8];
            *(float4*)&a[4] = *(const float4*)&As[kk][tr * 8 + 4];
            *(float4*)&b[0] = *(const float4*)&Bs[kk][tc * 4];
            #pragma unroll
            for (int m = 0; m < 8; ++m)
                #pragma unroll
                for (int n = 0; n < 4; ++n)
                    acc[m][n] = fmaf(a[m], b[n], acc[m][n]);
        }
        __syncthreads();
    }

    #pragma unroll
    for (int m = 0; m < 8; ++m) {
        const int r = row0 + tr * 8 + m;
        #pragma unroll
        for (int n = 0; n < 4; ++n) {
            const int c = tc * 4 + n;
            if (c < C_E) atomicAdd(&C[(size_t)r * C_E + c], acc[m][n]);
        }
    }
}

// =====================================================================
// Node GEMM partials: P[s][512][151], s = k-chunk of 256 (deterministic).
// Same register-tiled structure: thread tile 4x4, BM=64, BN=64, grid
// (8 rowblk, 3 colblk, 8 ksplit).
// =====================================================================
__global__ __launch_bounds__(256) void node_gemm(const float* __restrict__ A,
                                                 const float* __restrict__ S,
                                                 float* __restrict__ P) {
    __shared__ float As[32][68];
    __shared__ float Bs[32][68];
    const int tid = threadIdx.x;
    const int tr  = tid >> 4;
    const int tc  = tid & 15;
    const int r0  = blockIdx.x * 64;
    const int c0  = blockIdx.y * 64;
    const int kb  = blockIdx.z * 256;

    float acc[4][4];
    #pragma unroll
    for (int m = 0; m < 4; ++m)
        #pragma unroll
        for (int n = 0; n < 4; ++n) acc[m][n] = 0.f;

    for (int k0 = 0; k0 < 256; k0 += 32) {
        #pragma unroll
        for (int j = 0; j < 2; ++j) {
            const int f   = tid + 256 * j;
            const int row = f >> 3;
            const int kq  = f & 7;
            const float4 v = *(const float4*)(A + (size_t)(r0 + row) * D + kb + k0 + kq * 4);
            As[kq * 4 + 0][row] = v.x;
            As[kq * 4 + 1][row] = v.y;
            As[kq * 4 + 2][row] = v.z;
            As[kq * 4 + 3][row] = v.w;
        }
        #pragma unroll
        for (int j = 0; j < 8; ++j) {
            const int e = tid + 256 * j;
            const int k = e >> 6;
            const int c = e & 63;
            Bs[k][c] = (c0 + c < C_N) ? S[(size_t)(kb + k0 + k) * C_N + c0 + c] : 0.f;
        }
        __syncthreads();

        #pragma unroll 8
        for (int kk = 0; kk < 32; ++kk) {
            float a[4], b[4];
            *(float4*)&a[0] = *(const float4*)&As[kk][tr * 4];
            *(float4*)&b[0] = *(const float4*)&Bs[kk][tc * 4];
            #pragma unroll
            for (int m = 0; m < 4; ++m)
                #pragma unroll
                for (int n = 0; n < 4; ++n)
                    acc[m][n] = fmaf(a[m], b[n], acc[m][n]);
        }
        __syncthreads();
    }

    float* out = P + (size_t)blockIdx.z * (N_NODES * C_N);
    #pragma unroll
    for (int m = 0; m < 4; ++m) {
        const int r = r0 + tr * 4 + m;
        #pragma unroll
        for (int n = 0; n < 4; ++n) {
            const int c = c0 + tc * 4 + n;
            if (c < C_N) out[(size_t)r * C_N + c] = acc[m][n];
        }
    }
}

// =====================================================================
// Tiled transpose: schemaT[151][2048] = nodes_schema[2048][151]^T
// 32x32 LDS tiles, both global sides coalesced. grid (64, 5).
// =====================================================================
__global__ __launch_bounds__(256) void transpose_k(const float* __restrict__ S,
                                                   float* __restrict__ ST) {
    __shared__ float T[32][33];
    const int tid = threadIdx.x;
    const int d0  = blockIdx.x * 32;
    const int c0  = blockIdx.y * 32;
    #pragma unroll
    for (int j = 0; j < 4; ++j) {
        const int idx = tid + 256 * j;
        const int rr  = idx >> 5;    // d within tile
        const int cc  = idx & 31;    // c within tile
        T[cc][rr] = (c0 + cc < C_N) ? S[(size_t)(d0 + rr) * C_N + c0 + cc] : 0.f;
    }
    __syncthreads();
    #pragma unroll
    for (int j = 0; j < 4; ++j) {
        const int idx = tid + 256 * j;
        const int cc  = idx >> 5;
        const int rr  = idx & 31;
        if (c0 + cc < C_N)
            ST[(size_t)(c0 + cc) * D + d0 + rr] = T[cc][rr];
    }
}

// =====================================================================
// Reduce node partials -> raw_node_class, then row softmax -> att.
// One wave per row; att[:,0] = 0 (background never kept).
// =====================================================================
__global__ __launch_bounds__(256) void softmax_k(const float* __restrict__ np,
                                                 float* __restrict__ raw_out,
                                                 float* __restrict__ att) {
    const int w    = threadIdx.x >> 6;
    const int lane = threadIdx.x & 63;
    const int r    = blockIdx.x * 4 + w;
    const size_t base = (size_t)r * C_N;

    float v0 = 0.f, v1 = 0.f, v2 = 0.f;
    #pragma unroll
    for (int s = 0; s < 8; ++s) {
        const float* p = np + (size_t)s * (N_NODES * C_N) + base;
        v0 += p[lane];
        v1 += p[64 + lane];
        if (lane < C_N - 128) v2 += p[128 + lane];
    }
    raw_out[base + lane]      = v0;
    raw_out[base + 64 + lane] = v1;
    if (lane < C_N - 128) raw_out[base + 128 + lane] = v2;

    float m = fmaxf(v0, v1);
    if (lane < C_N - 128) m = fmaxf(m, v2);
    #pragma unroll
    for (int o = 32; o; o >>= 1) m = fmaxf(m, __shfl_xor(m, o));

    const float e0 = expf(v0 - m);
    const float e1 = expf(v1 - m);
    const float e2 = (lane < C_N - 128) ? expf(v2 - m) : 0.f;
    float ssum = e0 + e1 + e2;
    #pragma unroll
    for (int o = 32; o; o >>= 1) ssum += __shfl_xor(ssum, o);

    att[base + lane]      = (lane == 0) ? 0.f : (e0 / ssum);
    att[base + 64 + lane] = e1 / ssum;
    if (lane < C_N - 128) att[base + 128 + lane] = e2 / ssum;
}

// =====================================================================
// Per-class NMS. One block per class c in [1,150]. Bitonic sort
// (score desc, idx asc == stable argsort(-s)), parallel IoU bitmasks,
// wave-serial greedy scan, masked write-back.
// =====================================================================
__global__ __launch_bounds__(256) void nms_k(float* __restrict__ att,
                                             const float* __restrict__ boxes) {
    const int c = blockIdx.x + 1;
    __shared__ float  ss[512];
    __shared__ int    si[512];
    __shared__ float4 bs[512];
    __shared__ float  area[512];
    __shared__ unsigned long long msk[512][8];
    __shared__ unsigned long long rem[8];
    const int tid = threadIdx.x;

    for (int i = tid; i < 512; i += 256) {
        ss[i] = att[(size_t)i * C_N + c];
        si[i] = i;
    }
    __syncthreads();

    for (int k = 2; k <= 512; k <<= 1) {
        for (int j = k >> 1; j > 0; j >>= 1) {
            for (int i = tid; i < 512; i += 256) {
                const int ixj = i ^ j;
                if (ixj > i) {
                    const float sa = ss[i], sb = ss[ixj];
                    const int ia = si[i], ib = si[ixj];
                    const bool aFirst = (sa > sb) || (sa == sb && ia < ib);
                    const bool up = ((i & k) == 0);
                    if (up ? !aFirst : aFirst) {
                        ss[i] = sb; ss[ixj] = sa;
                        si[i] = ib; si[ixj] = ia;
                    }
                }
            }
            __syncthreads();
        }
    }

    for (int i = tid; i < 512; i += 256) {
        const float4 b = *(const float4*)(boxes + ((size_t)si[i] * C_N + c) * 4);
        bs[i] = b;
        area[i] = (b.z - b.x) * (b.w - b.y);
    }
    __syncthreads();

    for (int Wd = tid; Wd < 512 * 8; Wd += 256) {
        const int i = Wd >> 3;
        const int w = Wd & 7;
        unsigned long long m = 0ull;
        const int j0 = w * 64;
        if (j0 + 63 > i) {
            const float4 bi = bs[i];
            const float  ai = area[i];
            const int bstart = (i + 1 > j0) ? (i + 1 - j0) : 0;
            for (int b = bstart; b < 64; ++b) {
                const int j = j0 + b;
                const float4 bj = bs[j];
                const float lx = fmaxf(bi.x, bj.x);
                const float ly = fmaxf(bi.y, bj.y);
                const float rx = fminf(bi.z, bj.z);
                const float ry = fminf(bi.w, bj.w);
                const float ww = fmaxf(rx - lx, 0.f);
                const float hh = fmaxf(ry - ly, 0.f);
                const float inter = ww * hh;
                const float iou = inter / (ai + area[j] - inter + 1e-9f);
                if (iou > NMS_TH) m |= (1ull << b);
            }
        }
        msk[i][w] = m;
    }
    __syncthreads();

    if (tid < 64) {
        const int w = tid & 7;
        unsigned long long r = 0ull;
        for (int i = 0; i < 512; ++i) {
            const unsigned long long ri = __shfl(r, i >> 6);
            const bool keep = !((ri >> (i & 63)) & 1ull);
            if (keep) r |= msk[i][w];
        }
        if (tid < 8) rem[tid] = r;
    }
    __syncthreads();

    for (int p = tid; p < 512; p += 256) {
        const bool kp = !((rem[p >> 6] >> (p & 63)) & 1ull);
        att[(size_t)si[p] * C_N + c] = kp ? ss[p] : 0.f;
    }
}

// =====================================================================
// h_node_emb[512][2048] = att_masked[512][151] @ schemaT[151][2048]
// att staged TRANSPOSED in LDS -> per-c inner step = 2 broadcast b128s.
// =====================================================================
__global__ __launch_bounds__(256) void hnode_k(const float* __restrict__ attm,
                                               const float* __restrict__ ST,
                                               float* __restrict__ H) {
    __shared__ float alT[C_N + 1][8];   // [152][8], row = 32B (b128-aligned)
    const int r0 = blockIdx.y * 8;
    const int d  = blockIdx.x * 256 + threadIdx.x;

    for (int i = threadIdx.x; i < 152 * 8; i += 256) {
        const int cc = i >> 3;
        const int j  = i & 7;
        alT[cc][j] = (cc < C_N) ? attm[(size_t)(r0 + j) * C_N + cc] : 0.f;
    }
    __syncthreads();

    float acc[8] = {0.f, 0.f, 0.f, 0.f, 0.f, 0.f, 0.f, 0.f};
    #pragma unroll 4
    for (int cc = 0; cc < C_N; ++cc) {
        const float s = ST[(size_t)cc * D + d];
        float w[8];
        *(float4*)&w[0] = *(const float4*)&alT[cc][0];
        *(float4*)&w[4] = *(const float4*)&alT[cc][4];
        #pragma unroll
        for (int j = 0; j < 8; ++j)
            acc[j] = fmaf(w[j], s, acc[j]);
    }
    #pragma unroll
    for (int j = 0; j < 8; ++j)
        H[(size_t)(r0 + j) * D + d] = acc[j];
}

// =====================================================================
extern "C" void kernel_launch(void* const* d_in, const int* in_sizes, int n_in,
                              void* d_out, int out_size, void* d_ws, size_t ws_size,
                              hipStream_t stream) {
    (void)in_sizes; (void)n_in; (void)out_size; (void)ws_size;
    const float* node_emb     = (const float*)d_in[0];
    const float* edge_emb     = (const float*)d_in[1];
    const float* boxes        = (const float*)d_in[6];
    const float* nodes_schema = (const float*)d_in[7];
    const float* edges_schema = (const float*)d_in[8];
    float* out = (float*)d_out;
    float* ws  = (float*)d_ws;

    float* att = ws + W_ATT;
    float* sct = ws + W_SCT;
    float* np  = ws + W_NP;

    // h_edge_emb is exactly zero; raw_edge_class zeroed for atomic K-split.
    hipMemsetAsync(out + O_HEE, 0, (size_t)(N_EDGES * D) * sizeof(float), stream);
    hipMemsetAsync(out + O_REC, 0, (size_t)(N_EDGES * C_E) * sizeof(float), stream);

    edge_gemm<<<dim3(N_EDGES / EG_BM, 2048 / EG_KSPAN), 256, 0, stream>>>(
        edge_emb, edges_schema, out + O_REC);
    node_gemm<<<dim3(8, 3, 8), 256, 0, stream>>>(node_emb, nodes_schema, np);
    transpose_k<<<dim3(64, 5), 256, 0, stream>>>(nodes_schema, sct);
    softmax_k<<<N_NODES / 4, 256, 0, stream>>>(np, out + O_RNC, att);
    nms_k<<<C_N - 1, 256, 0, stream>>>(att, boxes);
    hnode_k<<<dim3(D / 256, N_NODES / 8), 256, 0, stream>>>(att, sct, out + O_HNE);
}